// Round 1
// baseline (1081.340 us; speedup 1.0000x reference)
//
#include <hip/hip_runtime.h>
#include <math.h>

typedef unsigned short u16;
typedef unsigned int   u32;
typedef unsigned long long u64;
typedef __attribute__((ext_vector_type(8))) short short8;
typedef __attribute__((ext_vector_type(4))) float f32x4;

#define R_N   16
#define HW_N  16384   // 128*128 coarse grid
#define P_N   8192    // points kept per instance
#define K0    512     // MLP layer-0 input dim (CH + CIN)
#define CH_N  256

// ---------- bf16 split helpers (x ~= hi + lo, each bf16 RNE) ----------
__device__ __forceinline__ u16 f2bf(float x) {
  u32 u = __float_as_uint(x);
  return (u16)((u + 0x7FFFu + ((u >> 16) & 1u)) >> 16);
}
__device__ __forceinline__ void split_bf(float x, u16 &h, u16 &l) {
  u16 hh = f2bf(x);
  float hf = __uint_as_float(((u32)hh) << 16);
  h = hh;
  l = f2bf(x - hf);
}

// ---------------- kernel 1: per-instance full bitonic sort ----------------
// key = (raw f32 bits of -|logit|) << 32 | index.  All values have sign bit
// set, so ascending u64 order == descending value order, ties by index.
__global__ __launch_bounds__(1024, 4) void topk_sort(const float* __restrict__ coarse,
                                                     u32* __restrict__ rank_of) {
  extern __shared__ u64 key[];   // 16384 * 8B = 128 KiB
  const int r = blockIdx.x;
  const float* src = coarse + r * HW_N;
  for (int i = threadIdx.x; i < HW_N; i += 1024) {
    float v = -fabsf(src[i]);
    key[i] = (((u64)__float_as_uint(v)) << 32) | (u32)i;
  }
  __syncthreads();
  for (int k = 2; k <= HW_N; k <<= 1) {
    for (int j = k >> 1; j > 0; j >>= 1) {
      for (int p = threadIdx.x; p < HW_N / 2; p += 1024) {
        int lo = p & (j - 1);
        int i  = ((p - lo) << 1) | lo;
        int ip = i | j;
        u64 a = key[i], b = key[ip];
        bool up = ((i & k) == 0);
        if ((a > b) == up) { key[i] = b; key[ip] = a; }
      }
      __syncthreads();
    }
  }
  // rank_of[lin] = position in top-k order, or ~0 if not selected
  for (int j = threadIdx.x; j < HW_N; j += 1024) {
    u32 lin = (u32)key[j];
    rank_of[r * HW_N + lin] = (j < P_N) ? (u32)j : 0xFFFFFFFFu;
  }
}

// ---------------- kernel 2: spatial-order stream compaction ----------------
// Emits the selected points in row-major (spatial) order with their ranks.
__global__ __launch_bounds__(1024, 4) void compact_spatial(const u32* __restrict__ rank_of,
                                                           u32* __restrict__ slin,
                                                           u32* __restrict__ srank) {
  const int r = blockIdx.x;
  __shared__ u32 wsum[16];
  __shared__ u32 wbase[17];
  const int tid = threadIdx.x;
  const int lane = tid & 63;
  const int w = tid >> 6;
  u32 running = 0;
  for (int it = 0; it < 16; ++it) {
    int i = it * 1024 + tid;
    u32 rk = rank_of[r * HW_N + i];
    bool f = (rk != 0xFFFFFFFFu);
    u64 m = __ballot(f);
    u32 pre = (u32)__popcll(m & ((1ull << lane) - 1ull));
    u32 cnt = (u32)__popcll(m);
    if (lane == 0) wsum[w] = cnt;
    __syncthreads();
    if (tid == 0) {
      u32 s = 0;
      for (int q = 0; q < 16; ++q) { wbase[q] = s; s += wsum[q]; }
      wbase[16] = s;
    }
    __syncthreads();
    if (f) {
      u32 pos = running + wbase[w] + pre;
      slin [r * P_N + pos] = (u32)i;
      srank[r * P_N + pos] = rk;
    }
    running += wbase[16];
    __syncthreads();
  }
}

// ---------------- kernel 3: weight transpose + bf16 hi/lo split ----------------
// W (K,N) f32 -> Wt_hi/Wt_lo (N,K) bf16, so B-fragments are contiguous 16B loads.
__global__ __launch_bounds__(256) void wprep(const float* __restrict__ W0,
                                             const float* __restrict__ W1,
                                             const float* __restrict__ W2,
                                             u16* __restrict__ w0h, u16* __restrict__ w0l,
                                             u16* __restrict__ w1h, u16* __restrict__ w1l,
                                             u16* __restrict__ w2h, u16* __restrict__ w2l) {
  int t = blockIdx.x * 256 + threadIdx.x;
  if (t < 131072) {
    int k = t >> 8, n = t & 255;
    u16 h, l; split_bf(W0[t], h, l);
    w0h[n * 512 + k] = h; w0l[n * 512 + k] = l;
  } else if (t < 196608) {
    int e = t - 131072; int k = e >> 8, n = e & 255;
    u16 h, l; split_bf(W1[e], h, l);
    w1h[n * 256 + k] = h; w1l[n * 256 + k] = l;
  } else if (t < 262144) {
    int e = t - 196608; int k = e >> 8, n = e & 255;
    u16 h, l; split_bf(W2[e], h, l);
    w2h[n * 256 + k] = h; w2l[n * 256 + k] = l;
  }
}

// ---------------- kernel 4: fused gather + PE + MLP ----------------
// One block = 32 spatially-consecutive points of one instance.
// LDS (66944 B, 2 blocks/CU):
//   [0,32768)      X_hi [32][512] bf16, XOR-swizzled      (reused: H_hi/H_lo after L0)
//   [32768,65536)  X_lo [32][512] bf16, XOR-swizzled      (reused: H2 f32 after L1)
//   [65536,..)     per-point metadata

__device__ __forceinline__ void stX4(u16* base, int row, int c, const u16* v) {
  int byte = ((row << 10) + (c << 1)) ^ ((row & 7) << 4);
  u64 pk = (u64)v[0] | ((u64)v[1] << 16) | ((u64)v[2] << 32) | ((u64)v[3] << 48);
  *(u64*)((char*)base + byte) = pk;
}

__device__ __forceinline__ short8 ldX(const u16* base, int row, int kk) {
  int byte = ((row << 10) + (kk << 1)) ^ ((row & 7) << 4);
  return *(const short8*)((const char*)base + byte);
}
__device__ __forceinline__ short8 ldH(const u16* base, int row, int kk) {
  int byte = ((row << 9) + (kk << 1)) ^ ((row & 7) << 4);
  return *(const short8*)((const char*)base + byte);
}

__device__ __forceinline__ void layer256(const u16* Hh, const u16* Hl,
                                         const u16* __restrict__ wh,
                                         const u16* __restrict__ wl,
                                         int lr, int lk, int Nw, f32x4 acc[2][4]) {
#pragma unroll 2
  for (int kb = 0; kb < 8; ++kb) {
    const int kk = kb * 32 + lk * 8;
    short8 a0h = ldH(Hh, lr, kk);
    short8 a0l = ldH(Hl, lr, kk);
    short8 a1h = ldH(Hh, 16 + lr, kk);
    short8 a1l = ldH(Hl, 16 + lr, kk);
#pragma unroll
    for (int nt = 0; nt < 4; ++nt) {
      const int n = Nw + nt * 16 + lr;
      short8 bh = *(const short8*)(wh + n * 256 + kk);
      short8 bl = *(const short8*)(wl + n * 256 + kk);
      acc[0][nt] = __builtin_amdgcn_mfma_f32_16x16x32_bf16(a0h, bh, acc[0][nt], 0, 0, 0);
      acc[0][nt] = __builtin_amdgcn_mfma_f32_16x16x32_bf16(a0l, bh, acc[0][nt], 0, 0, 0);
      acc[0][nt] = __builtin_amdgcn_mfma_f32_16x16x32_bf16(a0h, bl, acc[0][nt], 0, 0, 0);
      acc[1][nt] = __builtin_amdgcn_mfma_f32_16x16x32_bf16(a1h, bh, acc[1][nt], 0, 0, 0);
      acc[1][nt] = __builtin_amdgcn_mfma_f32_16x16x32_bf16(a1l, bh, acc[1][nt], 0, 0, 0);
      acc[1][nt] = __builtin_amdgcn_mfma_f32_16x16x32_bf16(a1h, bl, acc[1][nt], 0, 0, 0);
    }
  }
}

__global__ __launch_bounds__(256, 2) void fused_pts(
    const float* __restrict__ feat, const float* __restrict__ peg,
    const u16* __restrict__ w0h, const u16* __restrict__ w0l,
    const u16* __restrict__ w1h, const u16* __restrict__ w1l,
    const u16* __restrict__ w2h, const u16* __restrict__ w2l,
    const float* __restrict__ W3, const float* __restrict__ b0,
    const float* __restrict__ b1, const float* __restrict__ b2,
    const float* __restrict__ b3,
    const u32* __restrict__ slin, const u32* __restrict__ srank,
    float* __restrict__ out)
{
  extern __shared__ char smem[];
  u16* Xh = (u16*)smem;
  u16* Xl = (u16*)(smem + 32768);
  u16* Hh = (u16*)smem;                // after L0, reuse X_hi area
  u16* Hl = (u16*)(smem + 16384);
  float* H2 = (float*)(smem + 32768);  // after L1 reads done, reuse X_lo area
  int*  moff  = (int*)(smem + 65536);          // [4][32]
  float* mwgt = (float*)(smem + 66048);        // [4][32]
  u32*  mrank = (u32*)(smem + 66560);          // [32]
  float* mlx  = (float*)(smem + 66688);        // [32]
  float* mly  = (float*)(smem + 66816);        // [32]

  // XCD-contiguous remap: XCD x gets blocks [x*512, (x+1)*512) in swizzled space
  const int bid = (int)blockIdx.x;
  const int swz = (bid & 7) * 512 + (bid >> 3);
  const int r = swz >> 8;
  const int tile = swz & 255;
  const int tid = threadIdx.x;

  // ---- phase 0: point metadata ----
  if (tid < 32) {
    const int p = tid;
    u32 lin = slin [r * P_N + tile * 32 + p];
    u32 rk  = srank[r * P_N + tile * 32 + p];
    int iy = (int)(lin >> 7), ix = (int)(lin & 127u);
    float px = 0.00390625f + (float)ix * 0.0078125f;   // (ix+0.5)/128 exact
    float py = 0.00390625f + (float)iy * 0.0078125f;
    const float fsc = (float)(510.0 / 511.0);
    float gx = (2.0f * px) * fsc - 1.0f;
    float gy = (2.0f * py) * fsc - 1.0f;
    float xx = ((gx + 1.0f) * 128.0f - 1.0f) * 0.5f;
    float yy = ((gy + 1.0f) * 128.0f - 1.0f) * 0.5f;
    float x0f = floorf(xx), y0f = floorf(yy);
    float wx = xx - x0f, wy = yy - y0f;
    int x0 = (int)x0f, y0 = (int)y0f;
    int x1 = x0 + 1, y1 = y0 + 1;
    int cx0 = min(max(x0, 0), 127), cx1 = min(max(x1, 0), 127);
    int cy0 = min(max(y0, 0), 127), cy1 = min(max(y1, 0), 127);
    int vx0 = (x0 >= 0) & (x0 < 128), vx1 = (x1 >= 0) & (x1 < 128);
    int vy0 = (y0 >= 0) & (y0 < 128), vy1 = (y1 >= 0) & (y1 < 128);
    moff[p]      = cy0 * 128 + cx0;
    moff[32 + p] = cy0 * 128 + cx1;
    moff[64 + p] = cy1 * 128 + cx0;
    moff[96 + p] = cy1 * 128 + cx1;
    mwgt[p]      = (1.f - wx) * (1.f - wy) * (float)(vx0 & vy0);
    mwgt[32 + p] = wx * (1.f - wy) * (float)(vx1 & vy0);
    mwgt[64 + p] = (1.f - wx) * wy * (float)(vx0 & vy1);
    mwgt[96 + p] = wx * wy * (float)(vx1 & vy1);
    mrank[p] = rk;
    mlx[p] = 2.0f * px - 1.0f;
    mly[p] = 2.0f * py - 1.0f;
  }
  __syncthreads();

  // ---- phase 1: positional encoding -> X[:, 0:256] ----
  {
    const int p = tid & 31;
    const int h8 = tid >> 5;
    const float lx = mlx[p], ly = mly[p];
    const float TWO_PI = 6.283185307179586f;
    for (int c0 = h8 * 16; c0 < h8 * 16 + 16; c0 += 4) {
      u16 sh[4], sl[4], qh[4], ql[4];
#pragma unroll
      for (int q = 0; q < 4; ++q) {
        int c = c0 + q;
        float pr = TWO_PI * (lx * peg[c] + ly * peg[128 + c]);
        float sv = sinf(pr), cv = cosf(pr);
        split_bf(sv, sh[q], sl[q]);
        split_bf(cv, qh[q], ql[q]);
      }
      stX4(Xh, p, c0, sh);        stX4(Xl, p, c0, sl);
      stX4(Xh, p, c0 + 128, qh);  stX4(Xl, p, c0 + 128, ql);
    }
  }

  // ---- phase 2: bilinear feature gather -> X[:, 256:512] ----
  {
    const int p = tid & 31;
    const int cg = tid >> 5;
    const float* fb = feat + (size_t)r * (256 * HW_N);
    const int o0 = moff[p], o1 = moff[32 + p], o2 = moff[64 + p], o3 = moff[96 + p];
    const float q0 = mwgt[p], q1 = mwgt[32 + p], q2 = mwgt[64 + p], q3 = mwgt[96 + p];
    for (int c0 = cg * 32; c0 < cg * 32 + 32; c0 += 4) {
      u16 vh[4], vl[4];
#pragma unroll
      for (int q = 0; q < 4; ++q) {
        const float* fc = fb + (size_t)(c0 + q) * HW_N;
        float v = q0 * fc[o0] + q1 * fc[o1] + q2 * fc[o2] + q3 * fc[o3];
        split_bf(v, vh[q], vl[q]);
      }
      stX4(Xh, p, 256 + c0, vh);
      stX4(Xl, p, 256 + c0, vl);
    }
  }
  __syncthreads();

  const int wv = tid >> 6;
  const int l  = tid & 63;
  const int lr = l & 15;
  const int lk = l >> 4;
  const int Nw = wv * 64;

  f32x4 acc[2][4];

  // ---- layer 0: (32x512) @ (512x256), split-bf16 3-product ----
#pragma unroll
  for (int a = 0; a < 2; ++a)
#pragma unroll
    for (int b = 0; b < 4; ++b) acc[a][b] = (f32x4){0.f, 0.f, 0.f, 0.f};
#pragma unroll 2
  for (int kb = 0; kb < 16; ++kb) {
    const int kk = kb * 32 + lk * 8;
    short8 a0h = ldX(Xh, lr, kk);
    short8 a0l = ldX(Xl, lr, kk);
    short8 a1h = ldX(Xh, 16 + lr, kk);
    short8 a1l = ldX(Xl, 16 + lr, kk);
#pragma unroll
    for (int nt = 0; nt < 4; ++nt) {
      const int n = Nw + nt * 16 + lr;
      short8 bh = *(const short8*)(w0h + n * K0 + kk);
      short8 bl = *(const short8*)(w0l + n * K0 + kk);
      acc[0][nt] = __builtin_amdgcn_mfma_f32_16x16x32_bf16(a0h, bh, acc[0][nt], 0, 0, 0);
      acc[0][nt] = __builtin_amdgcn_mfma_f32_16x16x32_bf16(a0l, bh, acc[0][nt], 0, 0, 0);
      acc[0][nt] = __builtin_amdgcn_mfma_f32_16x16x32_bf16(a0h, bl, acc[0][nt], 0, 0, 0);
      acc[1][nt] = __builtin_amdgcn_mfma_f32_16x16x32_bf16(a1h, bh, acc[1][nt], 0, 0, 0);
      acc[1][nt] = __builtin_amdgcn_mfma_f32_16x16x32_bf16(a1l, bh, acc[1][nt], 0, 0, 0);
      acc[1][nt] = __builtin_amdgcn_mfma_f32_16x16x32_bf16(a1h, bl, acc[1][nt], 0, 0, 0);
    }
  }
  __syncthreads();   // all waves done reading X before H overwrites it
  // epilogue L0: bias + relu + split -> H
#pragma unroll
  for (int mt = 0; mt < 2; ++mt)
#pragma unroll
    for (int nt = 0; nt < 4; ++nt) {
      const int n = Nw + nt * 16 + lr;
      const float bv = b0[n];
#pragma unroll
      for (int j = 0; j < 4; ++j) {
        const int row = mt * 16 + lk * 4 + j;
        float h = fmaxf(acc[mt][nt][j] + bv, 0.f);
        u16 hh, hl; split_bf(h, hh, hl);
        int byte = ((row << 9) + (n << 1)) ^ ((row & 7) << 4);
        *(u16*)((char*)Hh + byte) = hh;
        *(u16*)((char*)Hl + byte) = hl;
      }
    }
  __syncthreads();

  // ---- layer 1 ----
#pragma unroll
  for (int a = 0; a < 2; ++a)
#pragma unroll
    for (int b = 0; b < 4; ++b) acc[a][b] = (f32x4){0.f, 0.f, 0.f, 0.f};
  layer256(Hh, Hl, w1h, w1l, lr, lk, Nw, acc);
  __syncthreads();
#pragma unroll
  for (int mt = 0; mt < 2; ++mt)
#pragma unroll
    for (int nt = 0; nt < 4; ++nt) {
      const int n = Nw + nt * 16 + lr;
      const float bv = b1[n];
#pragma unroll
      for (int j = 0; j < 4; ++j) {
        const int row = mt * 16 + lk * 4 + j;
        float h = fmaxf(acc[mt][nt][j] + bv, 0.f);
        u16 hh, hl; split_bf(h, hh, hl);
        int byte = ((row << 9) + (n << 1)) ^ ((row & 7) << 4);
        *(u16*)((char*)Hh + byte) = hh;
        *(u16*)((char*)Hl + byte) = hl;
      }
    }
  __syncthreads();

  // ---- layer 2 ----
#pragma unroll
  for (int a = 0; a < 2; ++a)
#pragma unroll
    for (int b = 0; b < 4; ++b) acc[a][b] = (f32x4){0.f, 0.f, 0.f, 0.f};
  layer256(Hh, Hl, w2h, w2l, lr, lk, Nw, acc);
  __syncthreads();   // waves done reading H; H2 overlaps X_lo (dead)
#pragma unroll
  for (int mt = 0; mt < 2; ++mt)
#pragma unroll
    for (int nt = 0; nt < 4; ++nt) {
      const int n = Nw + nt * 16 + lr;
      const float bv = b2[n];
#pragma unroll
      for (int j = 0; j < 4; ++j) {
        const int row = mt * 16 + lk * 4 + j;
        H2[row * 256 + n] = fmaxf(acc[mt][nt][j] + bv, 0.f);
      }
    }
  __syncthreads();

  // ---- final: out[p] = h2[p,:] . W3 + b3 ----
  {
    const int p = tid >> 3;
    const int g = tid & 7;
    float s = 0.f;
#pragma unroll 4
    for (int i = 0; i < 32; ++i) {
      int c = g * 32 + ((i + p * 4 + g) & 31);   // bank-spread permutation
      s += H2[p * 256 + c] * W3[c];
    }
    s += __shfl_xor(s, 1);
    s += __shfl_xor(s, 2);
    s += __shfl_xor(s, 4);
    if (g == 0) out[r * P_N + mrank[p]] = s + b3[0];
  }
}

// ---------------- launcher ----------------
extern "C" void kernel_launch(void* const* d_in, const int* in_sizes, int n_in,
                              void* d_out, int out_size, void* d_ws, size_t ws_size,
                              hipStream_t stream) {
  const float* coarse = (const float*)d_in[0];
  const float* feat   = (const float*)d_in[1];
  const float* peg    = (const float*)d_in[2];
  const float* W0 = (const float*)d_in[3];
  const float* b0 = (const float*)d_in[4];
  const float* W1 = (const float*)d_in[5];
  const float* b1 = (const float*)d_in[6];
  const float* W2 = (const float*)d_in[7];
  const float* b2 = (const float*)d_in[8];
  const float* W3 = (const float*)d_in[9];
  const float* b3 = (const float*)d_in[10];
  float* out = (float*)d_out;

  char* ws = (char*)d_ws;
  u32* rank_of = (u32*)ws;                              // 16*16384*4 = 1 MiB
  u32* slin    = (u32*)(ws + (1 << 20));                // 512 KiB
  u32* srank   = (u32*)(ws + (1 << 20) + (512 << 10));  // 512 KiB
  u16* w0h = (u16*)(ws + (2 << 20));
  u16* w0l = w0h + 131072;
  u16* w1h = w0l + 131072;
  u16* w1l = w1h + 65536;
  u16* w2h = w1l + 65536;
  u16* w2l = w2h + 65536;

  hipLaunchKernelGGL(wprep, dim3(1024), dim3(256), 0, stream,
                     W0, W1, W2, w0h, w0l, w1h, w1l, w2h, w2l);
  hipLaunchKernelGGL(topk_sort, dim3(R_N), dim3(1024), 131072, stream, coarse, rank_of);
  hipLaunchKernelGGL(compact_spatial, dim3(R_N), dim3(1024), 0, stream,
                     rank_of, slin, srank);
  hipLaunchKernelGGL(fused_pts, dim3(R_N * 256), dim3(256), 66944, stream,
                     feat, peg, w0h, w0l, w1h, w1l, w2h, w2l,
                     W3, b0, b1, b2, b3, slin, srank, out);
}

// Round 5
// 861.054 us; speedup vs baseline: 1.2558x; 1.2558x over previous
//
#include <hip/hip_runtime.h>
#include <math.h>

typedef unsigned short u16;
typedef unsigned int   u32;
typedef unsigned long long u64;
typedef __attribute__((ext_vector_type(8))) short short8;
typedef __attribute__((ext_vector_type(4))) float f32x4;

#define R_N   16
#define HW_N  16384   // 128*128 coarse grid
#define P_N   8192    // points kept per instance
#define K0    512     // MLP layer-0 input dim (CH + CIN)
#define CH_N  256
#define MB    128     // points per fused block

// ---------- bf16 split helpers (x ~= hi + lo, each bf16 RNE) ----------
__device__ __forceinline__ u16 f2bf(float x) {
  u32 u = __float_as_uint(x);
  return (u16)((u + 0x7FFFu + ((u >> 16) & 1u)) >> 16);
}
__device__ __forceinline__ void split_bf(float x, u16 &h, u16 &l) {
  u16 hh = f2bf(x);
  float hf = __uint_as_float(((u32)hh) << 16);
  h = hh;
  l = f2bf(x - hf);
}

// =============== kernel 1: sort + rank-scatter + spatial compaction ===============
// key = (raw f32 bits of -|logit|) << 32 | index.  All values have sign bit set,
// so ascending u64 order == descending value order, ties by lower index (== lax.top_k).
__global__ __launch_bounds__(1024) void topk_sort(const float* __restrict__ coarse,
                                                  u32* __restrict__ slin,
                                                  u32* __restrict__ srank) {
  extern __shared__ u64 key[];                 // 16384 * 8B = 128 KiB
  const int r = blockIdx.x;
  const int tid = threadIdx.x;
  const float* src = coarse + r * HW_N;
#pragma unroll
  for (int u = 0; u < 4; ++u) {
    const int i4 = (u * 1024 + tid) * 4;
    const float4 v = *(const float4*)(src + i4);
    key[i4 + 0] = (((u64)__float_as_uint(-fabsf(v.x))) << 32) | (u32)(i4 + 0);
    key[i4 + 1] = (((u64)__float_as_uint(-fabsf(v.y))) << 32) | (u32)(i4 + 1);
    key[i4 + 2] = (((u64)__float_as_uint(-fabsf(v.z))) << 32) | (u32)(i4 + 2);
    key[i4 + 3] = (((u64)__float_as_uint(-fabsf(v.w))) << 32) | (u32)(i4 + 3);
  }
  __syncthreads();
  for (int k = 2; k <= HW_N; k <<= 1) {
    for (int j = k >> 1; j > 0; j >>= 1) {
      int i_[8], ip_[8];
      u64 a_[8], b_[8];
#pragma unroll
      for (int u = 0; u < 8; ++u) {            // all 16 reads in flight
        const int p = u * 1024 + tid;
        const int lo = p & (j - 1);
        const int i = ((p - lo) << 1) | lo;
        i_[u] = i; ip_[u] = i | j;
        a_[u] = key[i]; b_[u] = key[i | j];
      }
#pragma unroll
      for (int u = 0; u < 8; ++u) {
        const bool up = ((i_[u] & k) == 0);
        if ((a_[u] > b_[u]) == up) { key[i_[u]] = b_[u]; key[ip_[u]] = a_[u]; }
      }
      __syncthreads();
    }
  }
  // pull sorted lin indices into registers, then overlay key[] with rank table
  u32 lin_r[16];
#pragma unroll
  for (int u = 0; u < 16; ++u) lin_r[u] = (u32)key[u * 1024 + tid];
  __syncthreads();
  u16* rnk = (u16*)key;                        // [16384] overlays dead key area
  u32* wsum  = (u32*)((char*)key + 32768);     // beyond rnk, still in key area
  u32* wbase = wsum + 16;
#pragma unroll
  for (int u = 0; u < 16; ++u)
    rnk[lin_r[u]] = (u < 8) ? (u16)(u * 1024 + tid) : (u16)0xFFFF;
  __syncthreads();
  // ballot stream-compaction in spatial (lin) order
  const int lane = tid & 63;
  const int w = tid >> 6;
  u32 running = 0;
  for (int it = 0; it < 16; ++it) {
    const int i = it * 1024 + tid;
    const u16 rk = rnk[i];
    const bool f = (rk != (u16)0xFFFF);
    const u64 m = __ballot(f);
    if (lane == 0) wsum[w] = (u32)__popcll(m);
    __syncthreads();
    if (tid == 0) {
      u32 s = 0;
      for (int q = 0; q < 16; ++q) { wbase[q] = s; s += wsum[q]; }
      wbase[16] = s;
    }
    __syncthreads();
    if (f) {
      const u32 pos = running + wbase[w] + (u32)__popcll(m & ((1ull << lane) - 1ull));
      slin [r * P_N + pos] = (u32)i;
      srank[r * P_N + pos] = (u32)rk;
    }
    running += wbase[16];
    __syncthreads();
  }
}

// =============== kernel 2: weight transpose + bf16 hi/lo split ===============
// Output-linear mapping: coalesced 2B writes; scattered 4B reads are L1/L2-absorbed.
__global__ __launch_bounds__(256) void wprep(const float* __restrict__ W0,
                                             const float* __restrict__ W1,
                                             const float* __restrict__ W2,
                                             u16* __restrict__ w0h, u16* __restrict__ w0l,
                                             u16* __restrict__ w1h, u16* __restrict__ w1l,
                                             u16* __restrict__ w2h, u16* __restrict__ w2l) {
  const int t = blockIdx.x * 256 + threadIdx.x;
  if (t < 131072) {                    // W0^T: t = n*512 + k
    const int n = t >> 9, k = t & 511;
    u16 h, l; split_bf(W0[k * 256 + n], h, l);
    w0h[t] = h; w0l[t] = l;
  } else if (t < 196608) {             // W1^T: e = n*256 + k
    const int e = t - 131072; const int n = e >> 8, k = e & 255;
    u16 h, l; split_bf(W1[k * 256 + n], h, l);
    w1h[e] = h; w1l[e] = l;
  } else {                             // W2^T
    const int e = t - 196608; const int n = e >> 8, k = e & 255;
    u16 h, l; split_bf(W2[k * 256 + n], h, l);
    w2h[e] = h; w2l[e] = l;
  }
}

// =============== kernel 3: fused gather + PE + 3-layer MLP + dot ===============
// 128 points/block, 512 threads (8 waves: 2M x 4N, 64x64 wave tiles).
// LDS: X/H hi+lo [128][256] bf16 (2*64 KiB, XOR-swizzled) reused across layers;
//      H2 f32 [128][256] overlays the same 128 KiB; metadata above 128 KiB.

__device__ __forceinline__ void st4(u16* base, int row, int c, const u16* v) {
  const int byte = ((row << 9) + (c << 1)) ^ ((row & 7) << 4);
  const u64 pk = (u64)v[0] | ((u64)v[1] << 16) | ((u64)v[2] << 32) | ((u64)v[3] << 48);
  *(u64*)((char*)base + byte) = pk;
}

__device__ __forceinline__ void kloop(const u16* Ah, const u16* Al,
                                      const u16* __restrict__ wh,
                                      const u16* __restrict__ wl,
                                      const int wstride, const int kofs,
                                      const int Mw, const int Nw,
                                      const int lr, const int lk,
                                      f32x4 acc[4][4]) {
#pragma unroll 2
  for (int kb = 0; kb < 8; ++kb) {
    const int kk = kb * 32 + lk * 8;
    short8 ah[4], al[4];
#pragma unroll
    for (int mt = 0; mt < 4; ++mt) {
      const int row = Mw + mt * 16 + lr;
      const int byte = ((row << 9) + (kk << 1)) ^ ((row & 7) << 4);
      ah[mt] = *(const short8*)((const char*)Ah + byte);
      al[mt] = *(const short8*)((const char*)Al + byte);
    }
#pragma unroll
    for (int nt = 0; nt < 4; ++nt) {
      const int n = Nw + nt * 16 + lr;
      const short8 bh = *(const short8*)(wh + n * wstride + kofs + kk);
      const short8 bl = *(const short8*)(wl + n * wstride + kofs + kk);
#pragma unroll
      for (int mt = 0; mt < 4; ++mt) {
        acc[mt][nt] = __builtin_amdgcn_mfma_f32_16x16x32_bf16(ah[mt], bh, acc[mt][nt], 0, 0, 0);
        acc[mt][nt] = __builtin_amdgcn_mfma_f32_16x16x32_bf16(al[mt], bh, acc[mt][nt], 0, 0, 0);
        acc[mt][nt] = __builtin_amdgcn_mfma_f32_16x16x32_bf16(ah[mt], bl, acc[mt][nt], 0, 0, 0);
      }
    }
  }
}

__device__ __forceinline__ void epiH(f32x4 acc[4][4], const float* __restrict__ bias,
                                     u16* Hh, u16* Hl,
                                     const int Mw, const int Nw, const int lr, const int lk) {
#pragma unroll
  for (int nt = 0; nt < 4; ++nt) {
    const int n = Nw + nt * 16 + lr;
    const float bv = bias[n];
#pragma unroll
    for (int mt = 0; mt < 4; ++mt) {
#pragma unroll
      for (int j = 0; j < 4; ++j) {
        const int row = Mw + mt * 16 + lk * 4 + j;
        const float h = fmaxf(acc[mt][nt][j] + bv, 0.f);
        u16 hh, hl; split_bf(h, hh, hl);
        const int byte = ((row << 9) + (n << 1)) ^ ((row & 7) << 4);
        *(u16*)((char*)Hh + byte) = hh;
        *(u16*)((char*)Hl + byte) = hl;
      }
    }
  }
}

__global__ __launch_bounds__(512, 2) void fused_pts(
    const float* __restrict__ feat, const float* __restrict__ peg,
    const u16* __restrict__ w0h, const u16* __restrict__ w0l,
    const u16* __restrict__ w1h, const u16* __restrict__ w1l,
    const u16* __restrict__ w2h, const u16* __restrict__ w2l,
    const float* __restrict__ W3, const float* __restrict__ b0,
    const float* __restrict__ b1, const float* __restrict__ b2,
    const float* __restrict__ b3,
    const u32* __restrict__ slin, const u32* __restrict__ srank,
    float* __restrict__ out)
{
  extern __shared__ char smem[];
  u16* Xh = (u16*)smem;                        // [128][256] bf16, 65536 B
  u16* Xl = (u16*)(smem + 65536);              // 65536 B
  int*   moff  = (int*)(smem + 131072);        // [4][128]
  float* mwgt  = (float*)(smem + 133120);      // [4][128]
  u32*   mrank = (u32*)(smem + 135168);        // [128]
  float* mlx   = (float*)(smem + 135680);      // [128]
  float* mly   = (float*)(smem + 136192);      // [128]  -> total 136704 B

  // bijective XCD swizzle: 1024 blocks, XCD x owns [x*128,(x+1)*128)
  const int bid = (int)blockIdx.x;
  const int swz = (bid & 7) * 128 + (bid >> 3);
  const int r = swz >> 6;
  const int tile = swz & 63;
  const int tid = threadIdx.x;

  // ---- metadata for this block's 128 points ----
  if (tid < MB) {
    const int p = tid;
    const u32 lin = slin [r * P_N + tile * MB + p];
    const u32 rk  = srank[r * P_N + tile * MB + p];
    const int iy = (int)(lin >> 7), ix = (int)(lin & 127u);
    const float px = 0.00390625f + (float)ix * 0.0078125f;   // (ix+0.5)/128
    const float py = 0.00390625f + (float)iy * 0.0078125f;
    const float fsc = (float)(510.0 / 511.0);
    const float gx = (2.0f * px) * fsc - 1.0f;
    const float gy = (2.0f * py) * fsc - 1.0f;
    const float xx = ((gx + 1.0f) * 128.0f - 1.0f) * 0.5f;
    const float yy = ((gy + 1.0f) * 128.0f - 1.0f) * 0.5f;
    const float x0f = floorf(xx), y0f = floorf(yy);
    const float wx = xx - x0f, wy = yy - y0f;
    const int x0 = (int)x0f, y0 = (int)y0f;
    const int x1 = x0 + 1, y1 = y0 + 1;
    const int cx0 = min(max(x0, 0), 127), cx1 = min(max(x1, 0), 127);
    const int cy0 = min(max(y0, 0), 127), cy1 = min(max(y1, 0), 127);
    const int vx0 = (x0 >= 0) & (x0 < 128), vx1 = (x1 >= 0) & (x1 < 128);
    const int vy0 = (y0 >= 0) & (y0 < 128), vy1 = (y1 >= 0) & (y1 < 128);
    moff[p]           = cy0 * 128 + cx0;
    moff[MB + p]      = cy0 * 128 + cx1;
    moff[2 * MB + p]  = cy1 * 128 + cx0;
    moff[3 * MB + p]  = cy1 * 128 + cx1;
    mwgt[p]           = (1.f - wx) * (1.f - wy) * (float)(vx0 & vy0);
    mwgt[MB + p]      = wx * (1.f - wy) * (float)(vx1 & vy0);
    mwgt[2 * MB + p]  = (1.f - wx) * wy * (float)(vx0 & vy1);
    mwgt[3 * MB + p]  = wx * wy * (float)(vx1 & vy1);
    mrank[p] = rk;
    mlx[p] = 2.0f * px - 1.0f;
    mly[p] = 2.0f * py - 1.0f;
  }
  __syncthreads();

  const int wv = tid >> 6;
  const int l  = tid & 63;
  const int lr = l & 15;
  const int lk = l >> 4;
  const int Mw = (wv >> 2) * 64;
  const int Nw = (wv & 3) * 64;

  f32x4 acc[4][4];
#pragma unroll
  for (int a = 0; a < 4; ++a)
#pragma unroll
    for (int b = 0; b < 4; ++b) acc[a][b] = (f32x4){0.f, 0.f, 0.f, 0.f};

  // ---- PE half: X[:,0:256] = [sin | cos] of 2*pi*(loc . pe_gauss) ----
  {
    const int p = tid & 127;
    const int grp = tid >> 7;                  // 4 groups x 32 proj channels
    const float lx = mlx[p], ly = mly[p];
#pragma unroll 2
    for (int c0 = grp * 32; c0 < grp * 32 + 32; c0 += 4) {
      u16 sh[4], sl[4], qh[4], ql[4];
#pragma unroll
      for (int q = 0; q < 4; ++q) {
        const int c = c0 + q;
        const float t = lx * peg[c] + ly * peg[128 + c];   // revolutions
        const float sv = __builtin_amdgcn_sinf(t);         // sin(2*pi*t)
        const float cv = __builtin_amdgcn_cosf(t);
        split_bf(sv, sh[q], sl[q]);
        split_bf(cv, qh[q], ql[q]);
      }
      st4(Xh, p, c0, sh);        st4(Xl, p, c0, sl);
      st4(Xh, p, 128 + c0, qh);  st4(Xl, p, 128 + c0, ql);
    }
  }
  __syncthreads();

  // ---- L0 K-half 0 (PE channels, global K 0..255) ----
  kloop(Xh, Xl, w0h, w0l, K0, 0, Mw, Nw, lr, lk, acc);
  __syncthreads();   // all waves done reading PE half

  // ---- gather half: X[:,0:256] = bilinear features (global K 256..511) ----
  {
    const int p = tid & 127;
    const int grp = tid >> 7;                  // 4 groups x 64 channels
    const float* fb = feat + (size_t)r * (256 * HW_N);
    const int o0 = moff[p], o1 = moff[MB + p], o2 = moff[2 * MB + p], o3 = moff[3 * MB + p];
    const float q0 = mwgt[p], q1 = mwgt[MB + p], q2 = mwgt[2 * MB + p], q3 = mwgt[3 * MB + p];
#pragma unroll 2
    for (int c0 = grp * 64; c0 < grp * 64 + 64; c0 += 4) {
      u16 vh[4], vl[4];
#pragma unroll
      for (int q = 0; q < 4; ++q) {
        const float* fc = fb + (size_t)(c0 + q) * HW_N;
        const float v = q0 * fc[o0] + q1 * fc[o1] + q2 * fc[o2] + q3 * fc[o3];
        split_bf(v, vh[q], vl[q]);
      }
      st4(Xh, p, c0, vh);
      st4(Xl, p, c0, vl);
    }
  }
  __syncthreads();

  // ---- L0 K-half 1 ----
  kloop(Xh, Xl, w0h, w0l, K0, 256, Mw, Nw, lr, lk, acc);
  __syncthreads();
  epiH(acc, b0, Xh, Xl, Mw, Nw, lr, lk);       // H overlays X
  __syncthreads();

  // ---- L1 ----
#pragma unroll
  for (int a = 0; a < 4; ++a)
#pragma unroll
    for (int b = 0; b < 4; ++b) acc[a][b] = (f32x4){0.f, 0.f, 0.f, 0.f};
  kloop(Xh, Xl, w1h, w1l, CH_N, 0, Mw, Nw, lr, lk, acc);
  __syncthreads();
  epiH(acc, b1, Xh, Xl, Mw, Nw, lr, lk);
  __syncthreads();

  // ---- L2 ----
#pragma unroll
  for (int a = 0; a < 4; ++a)
#pragma unroll
    for (int b = 0; b < 4; ++b) acc[a][b] = (f32x4){0.f, 0.f, 0.f, 0.f};
  kloop(Xh, Xl, w2h, w2l, CH_N, 0, Mw, Nw, lr, lk, acc);
  __syncthreads();   // waves done reading H; write H2 f32 over the full 128 KiB
  {
    char* H2 = smem;
#pragma unroll
    for (int nt = 0; nt < 4; ++nt) {
      const int n = Nw + nt * 16 + lr;
      const float bv = b2[n];
#pragma unroll
      for (int mt = 0; mt < 4; ++mt) {
#pragma unroll
        for (int j = 0; j < 4; ++j) {
          const int row = Mw + mt * 16 + lk * 4 + j;
          const int byte = ((row << 10) + (n << 2)) ^ ((row & 7) << 4);
          *(float*)(H2 + byte) = fmaxf(acc[mt][nt][j] + bv, 0.f);
        }
      }
    }
  }
  __syncthreads();

  // ---- final: out[rank(p)] = H2[p,:] . W3 + b3 ----
  {
    const int p = tid >> 2;
    const int g = tid & 3;
    const char* rowp = smem + (p << 10);
    float s = 0.f;
#pragma unroll
    for (int i = 0; i < 16; ++i) {
      const int byte = ((g << 8) + (i << 4)) ^ ((p & 7) << 4);
      const f32x4 v = *(const f32x4*)(rowp + byte);
      const int c = g * 64 + i * 4;
      s += v.x * W3[c] + v.y * W3[c + 1] + v.z * W3[c + 2] + v.w * W3[c + 3];
    }
    s += __shfl_xor(s, 1);
    s += __shfl_xor(s, 2);
    if (g == 0) out[r * P_N + mrank[p]] = s + b3[0];
  }
}

// ---------------- launcher ----------------
extern "C" void kernel_launch(void* const* d_in, const int* in_sizes, int n_in,
                              void* d_out, int out_size, void* d_ws, size_t ws_size,
                              hipStream_t stream) {
  const float* coarse = (const float*)d_in[0];
  const float* feat   = (const float*)d_in[1];
  const float* peg    = (const float*)d_in[2];
  const float* W0 = (const float*)d_in[3];
  const float* b0 = (const float*)d_in[4];
  const float* W1 = (const float*)d_in[5];
  const float* b1 = (const float*)d_in[6];
  const float* W2 = (const float*)d_in[7];
  const float* b2 = (const float*)d_in[8];
  const float* W3 = (const float*)d_in[9];
  const float* b3 = (const float*)d_in[10];
  float* out = (float*)d_out;

  char* ws = (char*)d_ws;
  u32* slin  = (u32*)ws;                        // 512 KiB
  u32* srank = (u32*)(ws + 524288);             // 512 KiB
  u16* w0h = (u16*)(ws + 1048576);              // 256 KiB each (W0), 128 KiB (W1/W2)
  u16* w0l = w0h + 131072;
  u16* w1h = w0l + 131072;
  u16* w1l = w1h + 65536;
  u16* w2h = w1l + 65536;
  u16* w2l = w2h + 65536;                       // ends at 2 MiB

  hipLaunchKernelGGL(wprep, dim3(1024), dim3(256), 0, stream,
                     W0, W1, W2, w0h, w0l, w1h, w1l, w2h, w2l);
  hipLaunchKernelGGL(topk_sort, dim3(R_N), dim3(1024), 131072, stream,
                     coarse, slin, srank);
  hipLaunchKernelGGL(fused_pts, dim3(1024), dim3(512), 136704, stream,
                     feat, peg, w0h, w0l, w1h, w1l, w2h, w2l,
                     W3, b0, b1, b2, b3, slin, srank, out);
}

// Round 9
// 829.122 us; speedup vs baseline: 1.3042x; 1.0385x over previous
//
#include <hip/hip_runtime.h>
#include <math.h>

typedef unsigned short u16;
typedef unsigned int   u32;
typedef unsigned long long u64;
typedef __attribute__((ext_vector_type(8))) short short8;
typedef __attribute__((ext_vector_type(4))) float f32x4;

#define R_N   16
#define HW_N  16384   // 128*128 coarse grid
#define P_N   8192    // points kept per instance
#define K0    512     // MLP layer-0 input dim (CH + CIN)
#define CH_N  256
#define MB    64      // points per fused block (64 -> 68.4KB LDS -> 2 blocks/CU)

// ---------- bf16 split helpers (x ~= hi + lo, each bf16 RNE) ----------
__device__ __forceinline__ u16 f2bf(float x) {
  u32 u = __float_as_uint(x);
  return (u16)((u + 0x7FFFu + ((u >> 16) & 1u)) >> 16);
}
__device__ __forceinline__ void split_bf(float x, u16 &h, u16 &l) {
  u16 hh = f2bf(x);
  float hf = __uint_as_float(((u32)hh) << 16);
  h = hh;
  l = f2bf(x - hf);
}

// =============== kernel 1: sort + rank-scatter + spatial compaction ===============
// key = (raw f32 bits of -|logit|) << 32 | index.  All values have sign bit set,
// so ascending u64 order == descending value order, ties by lower index (== lax.top_k).
// PAD(i) = i + (i>>4): breaks power-of-2 stride bank conflicts (32-way at j>=8
// with u64 keys on 32 banks -> ~1-2 way).  17408*8B = 139264 B LDS.
#define PAD(i) ((i) + ((i) >> 4))
__global__ __launch_bounds__(1024) void topk_sort(const float* __restrict__ coarse,
                                                  u32* __restrict__ slin,
                                                  u32* __restrict__ srank) {
  extern __shared__ u64 key[];                 // padded [17408]
  const int r = blockIdx.x;
  const int tid = threadIdx.x;
  const float* src = coarse + r * HW_N;
#pragma unroll
  for (int u = 0; u < 4; ++u) {
    const int i4 = (u * 1024 + tid) * 4;
    const float4 v = *(const float4*)(src + i4);
    key[PAD(i4 + 0)] = (((u64)__float_as_uint(-fabsf(v.x))) << 32) | (u32)(i4 + 0);
    key[PAD(i4 + 1)] = (((u64)__float_as_uint(-fabsf(v.y))) << 32) | (u32)(i4 + 1);
    key[PAD(i4 + 2)] = (((u64)__float_as_uint(-fabsf(v.z))) << 32) | (u32)(i4 + 2);
    key[PAD(i4 + 3)] = (((u64)__float_as_uint(-fabsf(v.w))) << 32) | (u32)(i4 + 3);
  }
  __syncthreads();
  for (int k = 2; k <= HW_N; k <<= 1) {
    for (int j = k >> 1; j > 0; j >>= 1) {
      int ia_[8], ib_[8];
      u64 a_[8], b_[8];
#pragma unroll
      for (int u = 0; u < 8; ++u) {            // all 16 reads in flight
        const int p = u * 1024 + tid;
        const int lo = p & (j - 1);
        const int i = ((p - lo) << 1) | lo;
        const int ia = PAD(i), ib = PAD(i | j);
        ia_[u] = (i & k) ? -ia - 1 : ia;       // sign carries the direction bit
        ib_[u] = ib;
        a_[u] = key[ia]; b_[u] = key[ib];
      }
#pragma unroll
      for (int u = 0; u < 8; ++u) {
        const bool up = (ia_[u] >= 0);
        const int ia = up ? ia_[u] : -ia_[u] - 1;
        if ((a_[u] > b_[u]) == up) { key[ia] = b_[u]; key[ib_[u]] = a_[u]; }
      }
      __syncthreads();
    }
  }
  // pull sorted lin indices into registers, then overlay key[] with rank table
  u32 lin_r[16];
#pragma unroll
  for (int u = 0; u < 16; ++u) lin_r[u] = (u32)key[PAD(u * 1024 + tid)];
  __syncthreads();
  u16* rnk = (u16*)key;                        // [16384] overlays dead key area
  u32* wsum  = (u32*)((char*)key + 32768);     // beyond rnk, still in key area
  u32* wbase = wsum + 16;
#pragma unroll
  for (int u = 0; u < 16; ++u)
    rnk[lin_r[u]] = (u < 8) ? (u16)(u * 1024 + tid) : (u16)0xFFFF;
  __syncthreads();
  // ballot stream-compaction in spatial (lin) order
  const int lane = tid & 63;
  const int w = tid >> 6;
  u32 running = 0;
  for (int it = 0; it < 16; ++it) {
    const int i = it * 1024 + tid;
    const u16 rk = rnk[i];
    const bool f = (rk != (u16)0xFFFF);
    const u64 m = __ballot(f);
    if (lane == 0) wsum[w] = (u32)__popcll(m);
    __syncthreads();
    if (tid == 0) {
      u32 s = 0;
      for (int q = 0; q < 16; ++q) { wbase[q] = s; s += wsum[q]; }
      wbase[16] = s;
    }
    __syncthreads();
    if (f) {
      const u32 pos = running + wbase[w] + (u32)__popcll(m & ((1ull << lane) - 1ull));
      slin [r * P_N + pos] = (u32)i;
      srank[r * P_N + pos] = (u32)rk;
    }
    running += wbase[16];
    __syncthreads();
  }
}

// =============== kernel 2: weight transpose + bf16 hi/lo split ===============
// Output-linear mapping: coalesced 2B writes; scattered 4B reads are L1/L2-absorbed.
__global__ __launch_bounds__(256) void wprep(const float* __restrict__ W0,
                                             const float* __restrict__ W1,
                                             const float* __restrict__ W2,
                                             u16* __restrict__ w0h, u16* __restrict__ w0l,
                                             u16* __restrict__ w1h, u16* __restrict__ w1l,
                                             u16* __restrict__ w2h, u16* __restrict__ w2l) {
  const int t = blockIdx.x * 256 + threadIdx.x;
  if (t < 131072) {                    // W0^T: t = n*512 + k
    const int n = t >> 9, k = t & 511;
    u16 h, l; split_bf(W0[k * 256 + n], h, l);
    w0h[t] = h; w0l[t] = l;
  } else if (t < 196608) {             // W1^T: e = n*256 + k
    const int e = t - 131072; const int n = e >> 8, k = e & 255;
    u16 h, l; split_bf(W1[k * 256 + n], h, l);
    w1h[e] = h; w1l[e] = l;
  } else {                             // W2^T
    const int e = t - 196608; const int n = e >> 8, k = e & 255;
    u16 h, l; split_bf(W2[k * 256 + n], h, l);
    w2h[e] = h; w2l[e] = l;
  }
}

// =============== kernel 3: fused gather + PE + 3-layer MLP + dot ===============
// 64 points/block, 256 threads (4 waves, each owns a 64x64 output tile: Nw=wv*64).
// LDS 68352 B -> 2 blocks/CU for cross-block phase overlap (gather of block A
// hides under MFMA of block B).
// LDS: X/H hi+lo [64][256] bf16 (2*32 KiB, XOR-swizzled) reused across layers;
//      H2 f32 [64][256] overlays the same 64 KiB; metadata above.

__device__ __forceinline__ void st4(u16* base, int row, int c, const u16* v) {
  const int byte = ((row << 9) + (c << 1)) ^ ((row & 7) << 4);
  const u64 pk = (u64)v[0] | ((u64)v[1] << 16) | ((u64)v[2] << 32) | ((u64)v[3] << 48);
  *(u64*)((char*)base + byte) = pk;
}

__device__ __forceinline__ void kloop(const u16* Ah, const u16* Al,
                                      const u16* __restrict__ wh,
                                      const u16* __restrict__ wl,
                                      const int wstride, const int kofs,
                                      const int Nw,
                                      const int lr, const int lk,
                                      f32x4 acc[4][4]) {
#pragma unroll 2
  for (int kb = 0; kb < 8; ++kb) {
    const int kk = kb * 32 + lk * 8;
    short8 ah[4], al[4];
#pragma unroll
    for (int mt = 0; mt < 4; ++mt) {
      const int row = mt * 16 + lr;
      const int byte = ((row << 9) + (kk << 1)) ^ ((row & 7) << 4);
      ah[mt] = *(const short8*)((const char*)Ah + byte);
      al[mt] = *(const short8*)((const char*)Al + byte);
    }
#pragma unroll
    for (int nt = 0; nt < 4; ++nt) {
      const int n = Nw + nt * 16 + lr;
      const short8 bh = *(const short8*)(wh + n * wstride + kofs + kk);
      const short8 bl = *(const short8*)(wl + n * wstride + kofs + kk);
#pragma unroll
      for (int mt = 0; mt < 4; ++mt) {
        acc[mt][nt] = __builtin_amdgcn_mfma_f32_16x16x32_bf16(ah[mt], bh, acc[mt][nt], 0, 0, 0);
        acc[mt][nt] = __builtin_amdgcn_mfma_f32_16x16x32_bf16(al[mt], bh, acc[mt][nt], 0, 0, 0);
        acc[mt][nt] = __builtin_amdgcn_mfma_f32_16x16x32_bf16(ah[mt], bl, acc[mt][nt], 0, 0, 0);
      }
    }
  }
}

__device__ __forceinline__ void epiH(f32x4 acc[4][4], const float* __restrict__ bias,
                                     u16* Hh, u16* Hl,
                                     const int Nw, const int lr, const int lk) {
#pragma unroll
  for (int nt = 0; nt < 4; ++nt) {
    const int n = Nw + nt * 16 + lr;
    const float bv = bias[n];
#pragma unroll
    for (int mt = 0; mt < 4; ++mt) {
#pragma unroll
      for (int j = 0; j < 4; ++j) {
        const int row = mt * 16 + lk * 4 + j;
        const float h = fmaxf(acc[mt][nt][j] + bv, 0.f);
        u16 hh, hl; split_bf(h, hh, hl);
        const int byte = ((row << 9) + (n << 1)) ^ ((row & 7) << 4);
        *(u16*)((char*)Hh + byte) = hh;
        *(u16*)((char*)Hl + byte) = hl;
      }
    }
  }
}

__global__ __launch_bounds__(256, 2) void fused_pts(
    const float* __restrict__ feat, const float* __restrict__ peg,
    const u16* __restrict__ w0h, const u16* __restrict__ w0l,
    const u16* __restrict__ w1h, const u16* __restrict__ w1l,
    const u16* __restrict__ w2h, const u16* __restrict__ w2l,
    const float* __restrict__ W3, const float* __restrict__ b0,
    const float* __restrict__ b1, const float* __restrict__ b2,
    const float* __restrict__ b3,
    const u32* __restrict__ slin, const u32* __restrict__ srank,
    float* __restrict__ out)
{
  extern __shared__ char smem[];
  u16* Xh = (u16*)smem;                        // [64][256] bf16, 32768 B
  u16* Xl = (u16*)(smem + 32768);              // 32768 B
  int*   moff  = (int*)(smem + 65536);         // [4][64]  1024 B
  float* mwgt  = (float*)(smem + 66560);       // [4][64]  1024 B
  u32*   mrank = (u32*)(smem + 67584);         // [64]      256 B
  float* mlx   = (float*)(smem + 67840);       // [64]      256 B
  float* mly   = (float*)(smem + 68096);       // [64]      256 B -> total 68352 B

  // bijective XCD swizzle: 2048 blocks, XCD x owns [x*256,(x+1)*256)
  const int bid = (int)blockIdx.x;
  const int swz = (bid & 7) * 256 + (bid >> 3);
  const int r = swz >> 7;
  const int tile = swz & 127;
  const int tid = threadIdx.x;

  // ---- metadata for this block's 64 points ----
  if (tid < MB) {
    const int p = tid;
    const u32 lin = slin [r * P_N + tile * MB + p];
    const u32 rk  = srank[r * P_N + tile * MB + p];
    const int iy = (int)(lin >> 7), ix = (int)(lin & 127u);
    const float px = 0.00390625f + (float)ix * 0.0078125f;   // (ix+0.5)/128
    const float py = 0.00390625f + (float)iy * 0.0078125f;
    const float fsc = (float)(510.0 / 511.0);
    const float gx = (2.0f * px) * fsc - 1.0f;
    const float gy = (2.0f * py) * fsc - 1.0f;
    const float xx = ((gx + 1.0f) * 128.0f - 1.0f) * 0.5f;
    const float yy = ((gy + 1.0f) * 128.0f - 1.0f) * 0.5f;
    const float x0f = floorf(xx), y0f = floorf(yy);
    const float wx = xx - x0f, wy = yy - y0f;
    const int x0 = (int)x0f, y0 = (int)y0f;
    const int x1 = x0 + 1, y1 = y0 + 1;
    const int cx0 = min(max(x0, 0), 127), cx1 = min(max(x1, 0), 127);
    const int cy0 = min(max(y0, 0), 127), cy1 = min(max(y1, 0), 127);
    const int vx0 = (x0 >= 0) & (x0 < 128), vx1 = (x1 >= 0) & (x1 < 128);
    const int vy0 = (y0 >= 0) & (y0 < 128), vy1 = (y1 >= 0) & (y1 < 128);
    moff[p]           = cy0 * 128 + cx0;
    moff[MB + p]      = cy0 * 128 + cx1;
    moff[2 * MB + p]  = cy1 * 128 + cx0;
    moff[3 * MB + p]  = cy1 * 128 + cx1;
    mwgt[p]           = (1.f - wx) * (1.f - wy) * (float)(vx0 & vy0);
    mwgt[MB + p]      = wx * (1.f - wy) * (float)(vx1 & vy0);
    mwgt[2 * MB + p]  = (1.f - wx) * wy * (float)(vx0 & vy1);
    mwgt[3 * MB + p]  = wx * wy * (float)(vx1 & vy1);
    mrank[p] = rk;
    mlx[p] = 2.0f * px - 1.0f;
    mly[p] = 2.0f * py - 1.0f;
  }
  __syncthreads();

  const int wv = tid >> 6;                     // 4 waves
  const int l  = tid & 63;
  const int lr = l & 15;
  const int lk = l >> 4;
  const int Nw = wv * 64;

  f32x4 acc[4][4];
#pragma unroll
  for (int a = 0; a < 4; ++a)
#pragma unroll
    for (int b = 0; b < 4; ++b) acc[a][b] = (f32x4){0.f, 0.f, 0.f, 0.f};

  // ---- PE half: X[:,0:256] = [sin | cos] of 2*pi*(loc . pe_gauss) ----
  {
    const int p = tid & 63;
    const int grp = tid >> 6;                  // 4 groups x 32 proj channels
    const float lx = mlx[p], ly = mly[p];
#pragma unroll 2
    for (int c0 = grp * 32; c0 < grp * 32 + 32; c0 += 4) {
      u16 sh[4], sl[4], qh[4], ql[4];
#pragma unroll
      for (int q = 0; q < 4; ++q) {
        const int c = c0 + q;
        const float t = lx * peg[c] + ly * peg[128 + c];   // revolutions
        const float sv = __builtin_amdgcn_sinf(t);         // sin(2*pi*t)
        const float cv = __builtin_amdgcn_cosf(t);
        split_bf(sv, sh[q], sl[q]);
        split_bf(cv, qh[q], ql[q]);
      }
      st4(Xh, p, c0, sh);        st4(Xl, p, c0, sl);
      st4(Xh, p, 128 + c0, qh);  st4(Xl, p, 128 + c0, ql);
    }
  }
  __syncthreads();

  // ---- L0 K-half 0 (PE channels, global K 0..255) ----
  kloop(Xh, Xl, w0h, w0l, K0, 0, Nw, lr, lk, acc);
  __syncthreads();   // all waves done reading PE half

  // ---- gather half: X[:,0:256] = bilinear features (global K 256..511) ----
  {
    const int p = tid & 63;
    const int grp = tid >> 6;                  // 4 groups x 64 channels
    const float* fb = feat + (size_t)r * (256 * HW_N);
    const int o0 = moff[p], o1 = moff[MB + p], o2 = moff[2 * MB + p], o3 = moff[3 * MB + p];
    const float q0 = mwgt[p], q1 = mwgt[MB + p], q2 = mwgt[2 * MB + p], q3 = mwgt[3 * MB + p];
#pragma unroll 2
    for (int c0 = grp * 64; c0 < grp * 64 + 64; c0 += 4) {
      u16 vh[4], vl[4];
#pragma unroll
      for (int q = 0; q < 4; ++q) {
        const float* fc = fb + (size_t)(c0 + q) * HW_N;
        const float v = q0 * fc[o0] + q1 * fc[o1] + q2 * fc[o2] + q3 * fc[o3];
        split_bf(v, vh[q], vl[q]);
      }
      st4(Xh, p, c0, vh);
      st4(Xl, p, c0, vl);
    }
  }
  __syncthreads();

  // ---- L0 K-half 1 ----
  kloop(Xh, Xl, w0h, w0l, K0, 256, Nw, lr, lk, acc);
  __syncthreads();
  epiH(acc, b0, Xh, Xl, Nw, lr, lk);           // H overlays X
  __syncthreads();

  // ---- L1 ----
#pragma unroll
  for (int a = 0; a < 4; ++a)
#pragma unroll
    for (int b = 0; b < 4; ++b) acc[a][b] = (f32x4){0.f, 0.f, 0.f, 0.f};
  kloop(Xh, Xl, w1h, w1l, CH_N, 0, Nw, lr, lk, acc);
  __syncthreads();
  epiH(acc, b1, Xh, Xl, Nw, lr, lk);
  __syncthreads();

  // ---- L2 ----
#pragma unroll
  for (int a = 0; a < 4; ++a)
#pragma unroll
    for (int b = 0; b < 4; ++b) acc[a][b] = (f32x4){0.f, 0.f, 0.f, 0.f};
  kloop(Xh, Xl, w2h, w2l, CH_N, 0, Nw, lr, lk, acc);
  __syncthreads();   // waves done reading H; write H2 f32 over the 64 KiB
  {
    char* H2 = smem;
#pragma unroll
    for (int nt = 0; nt < 4; ++nt) {
      const int n = Nw + nt * 16 + lr;
      const float bv = b2[n];
#pragma unroll
      for (int mt = 0; mt < 4; ++mt) {
#pragma unroll
        for (int j = 0; j < 4; ++j) {
          const int row = mt * 16 + lk * 4 + j;
          const int byte = ((row << 10) + (n << 2)) ^ ((row & 7) << 4);
          *(float*)(H2 + byte) = fmaxf(acc[mt][nt][j] + bv, 0.f);
        }
      }
    }
  }
  __syncthreads();

  // ---- final: out[rank(p)] = H2[p,:] . W3 + b3 ----
  {
    const int p = tid >> 2;                    // 64 points
    const int g = tid & 3;
    const char* rowp = smem + (p << 10);
    float s = 0.f;
#pragma unroll
    for (int i = 0; i < 16; ++i) {
      const int ie = (i + g * 4 + p) & 15;     // rotate to spread banks
      const int byte = ((g << 8) + (ie << 4)) ^ ((p & 7) << 4);
      const f32x4 v = *(const f32x4*)(rowp + byte);
      const int c = g * 64 + ie * 4;
      s += v.x * W3[c] + v.y * W3[c + 1] + v.z * W3[c + 2] + v.w * W3[c + 3];
    }
    s += __shfl_xor(s, 1);
    s += __shfl_xor(s, 2);
    if (g == 0) out[r * P_N + mrank[p]] = s + b3[0];
  }
}

// ---------------- launcher ----------------
extern "C" void kernel_launch(void* const* d_in, const int* in_sizes, int n_in,
                              void* d_out, int out_size, void* d_ws, size_t ws_size,
                              hipStream_t stream) {
  const float* coarse = (const float*)d_in[0];
  const float* feat   = (const float*)d_in[1];
  const float* peg    = (const float*)d_in[2];
  const float* W0 = (const float*)d_in[3];
  const float* b0 = (const float*)d_in[4];
  const float* W1 = (const float*)d_in[5];
  const float* b1 = (const float*)d_in[6];
  const float* W2 = (const float*)d_in[7];
  const float* b2 = (const float*)d_in[8];
  const float* W3 = (const float*)d_in[9];
  const float* b3 = (const float*)d_in[10];
  float* out = (float*)d_out;

  char* ws = (char*)d_ws;
  u32* slin  = (u32*)ws;                        // 512 KiB
  u32* srank = (u32*)(ws + 524288);             // 512 KiB
  u16* w0h = (u16*)(ws + 1048576);              // 256 KiB each (W0), 128 KiB (W1/W2)
  u16* w0l = w0h + 131072;
  u16* w1h = w0l + 131072;
  u16* w1l = w1h + 65536;
  u16* w2h = w1l + 65536;
  u16* w2l = w2h + 65536;                       // ends at 2 MiB

  hipLaunchKernelGGL(wprep, dim3(1024), dim3(256), 0, stream,
                     W0, W1, W2, w0h, w0l, w1h, w1l, w2h, w2l);
  hipLaunchKernelGGL(topk_sort, dim3(R_N), dim3(1024), 139264, stream,
                     coarse, slin, srank);
  hipLaunchKernelGGL(fused_pts, dim3(2048), dim3(256), 68352, stream,
                     feat, peg, w0h, w0l, w1h, w1l, w2h, w2l,
                     W3, b0, b1, b2, b3, slin, srank, out);
}